// Round 4
// baseline (455.674 us; speedup 1.0000x reference)
//
#include <hip/hip_runtime.h>
#include <hip/hip_bf16.h>
#include <math.h>

#define B_ 32768
#define F_ 512
#define H_ 256
#define C_ 100
#define CP2 128  // C padded to 8*16 for MFMA c-tiles (one per wave)
#define E_ 8

typedef __attribute__((ext_vector_type(8))) short bf16x8;
typedef __attribute__((ext_vector_type(4))) float f32x4;

__device__ __forceinline__ unsigned short f2b(float f) {
    unsigned int u = __float_as_uint(f);
    return (unsigned short)((u + 0x7fffu + ((u >> 16) & 1u)) >> 16);
}

__device__ __forceinline__ void gll16(const void* g, void* l) {
    __builtin_amdgcn_global_load_lds((__attribute__((address_space(1))) void*)(g),
                                     (__attribute__((address_space(3))) void*)(l),
                                     16, 0, 0);
}

// ---------------- K0b: W1 [E][F][H] f32 -> W1t [E][H][F] bf16 ----------------
__global__ __launch_bounds__(256) void k0_tr_w1(const float* __restrict__ W1,
                                                unsigned short* __restrict__ w1t) {
    __shared__ float tile[32][33];
    int e = blockIdx.z, fb = blockIdx.x * 32, hb = blockIdx.y * 32;
    int tx = threadIdx.x, ty = threadIdx.y;
    #pragma unroll
    for (int j = 0; j < 4; ++j)
        tile[ty + 8 * j][tx] = W1[((size_t)(e * F_ + fb + ty + 8 * j)) * H_ + hb + tx];
    __syncthreads();
    #pragma unroll
    for (int j = 0; j < 4; ++j)
        w1t[((size_t)(e * H_ + hb + ty + 8 * j)) * F_ + fb + tx] = f2b(tile[tx][ty + 8 * j]);
}

// ---------------- K0c: W2 [E][H][C] f32 -> W2t [E][CP2][H] bf16 (zero-padded) ----------------
__global__ __launch_bounds__(256) void k0_cvt_w2(const float* __restrict__ W2,
                                                 unsigned short* __restrict__ w2t) {
    int idx = blockIdx.x * 256 + threadIdx.x;
    if (idx >= E_ * CP2 * H_) return;
    int e = idx / (CP2 * H_);
    int r = idx - e * (CP2 * H_);
    int c = r / H_, h = r - c * H_;
    float v = (c < C_) ? W2[((size_t)(e * H_ + h)) * C_ + c] : 0.0f;
    w2t[idx] = f2b(v);
}

// ---------------- K1: fp64 gating, top-2, part_sizes + fused x->bf16 convert ----------------
__global__ __launch_bounds__(256) void k1_gate(const float* __restrict__ x,
                                               const float* __restrict__ Wg,
                                               unsigned short* __restrict__ xb,
                                               int* __restrict__ routes,
                                               float* __restrict__ part) {
    __shared__ float sWg[F_ * E_];
    __shared__ int cnt[E_];
    int tid = threadIdx.x;
    for (int i = tid; i < F_ * E_; i += 256) sWg[i] = Wg[i];
    if (tid < E_) cnt[tid] = 0;
    __syncthreads();

    int r = tid >> 3, eidx = tid & 7;
    int row = blockIdx.x * 32 + r;
    const float* xr = x + (size_t)row * F_;
    double acc = 0.0;
    for (int f = 0; f < F_; f += 4) {
        float4 xv = *(const float4*)(xr + f);
        acc += (double)xv.x * (double)sWg[(f + 0) * 8 + eidx];
        acc += (double)xv.y * (double)sWg[(f + 1) * 8 + eidx];
        acc += (double)xv.z * (double)sWg[(f + 2) * 8 + eidx];
        acc += (double)xv.w * (double)sWg[(f + 3) * 8 + eidx];
    }
    // top-1 (ties -> lower index), butterfly within aligned groups of 8 lanes
    double v = acc; int ie = eidx;
    #pragma unroll
    for (int off = 1; off < 8; off <<= 1) {
        double ov = __shfl_xor(v, off);
        int oi = __shfl_xor(ie, off);
        if (ov > v || (ov == v && oi < ie)) { v = ov; ie = oi; }
    }
    int e1 = ie;
    double v2 = (eidx == e1) ? -1e300 : acc; int ie2 = eidx;
    #pragma unroll
    for (int off = 1; off < 8; off <<= 1) {
        double ov = __shfl_xor(v2, off);
        int oi = __shfl_xor(ie2, off);
        if (ov > v2 || (ov == v2 && oi < ie2)) { v2 = ov; ie2 = oi; }
    }
    int e2 = ie2;
    if (eidx == 0) {
        routes[row] = e1 | (e2 << 3);
        atomicAdd(&cnt[e1], 1);
        atomicAdd(&cnt[e2], 1);
    }
    __syncthreads();
    if (tid < E_) atomicAdd(&part[tid], (float)cnt[tid]);

    // fused x -> bf16 conversion (rows L1/L2-hot from the gate loop)
    const float4* xs = (const float4*)(x + (size_t)blockIdx.x * 32 * F_);
    ushort4* xd = (ushort4*)(xb + (size_t)blockIdx.x * 32 * F_);
    #pragma unroll
    for (int i = 0; i < 16; ++i) {
        float4 xv = xs[tid + i * 256];
        ushort4 o;
        o.x = f2b(xv.x); o.y = f2b(xv.y); o.z = f2b(xv.z); o.w = f2b(xv.w);
        xd[tid + i * 256] = o;
    }
}

// ---------------- K2: fused MoE — one block = 128 rows x ALL 8 experts ----------------
// 512 thr (8 waves: mg=row-half 0/1, ng=h-quarter 0..3), 256 blocks = 1/CU.
// LDS 163840 B: A [0,131072) = 128 rows x 512 k bf16, staged ONCE (swizzled gll16),
//               sH [131072,163840) = 64 rows x 256 h bf16 per pass, 5-bit XOR chunk swizzle.
// GEMM1 (h = relu(x@W1)): zero barriers; A from resident LDS; B (w1t) straight
//   from global, reg-dbuffered one K-step (the mg-pair's duplicate loads dedup in L1).
//   L2 W1 traffic halves vs BM=64 (512 MB total).
// GEMM2 (preds^T = W2 @ h): c-split — wave w owns c-tile w (CP2=128 = 8x16), its
//   W2 slice lives in 8 regs across BOTH row-half passes -> zero W2 duplication.
//   Two passes (rows 0-63, 64-127) over one 32 KB sH buffer; 4 barriers/expert.
// Softmax/combine is k3's job again (c now spans waves; preds stays L3-hot).
__global__ __launch_bounds__(512, 2) void k2_moe(const unsigned short* __restrict__ xbf,
                                                 const unsigned short* __restrict__ w1t,
                                                 const unsigned short* __restrict__ w2t,
                                                 const float* __restrict__ b1,
                                                 const float* __restrict__ b2,
                                                 float* __restrict__ preds) {
    __shared__ __align__(16) char smem[163840];
    char* sH = smem + 131072;
    const int tid = threadIdx.x;
    const int w = tid >> 6, lane = tid & 63;
    const int q = lane >> 4, ln = lane & 15;
    const int mg = w >> 2;   // row-half (GEMM1)
    const int ng = w & 3;    // h-quarter (GEMM1)
    const int rowBase = blockIdx.x * 128;

    // ---- stage the whole 128x512 A-tile once (16 x 8KiB sub-tiles, swizzled slots) ----
    const int sub = lane >> 3;
    const int j8 = (lane & 7) ^ sub;
    const unsigned short* srcA0 = xbf + (size_t)(rowBase + mg * 64 + ng * 8 + sub) * F_ + 8 * j8;
    char* dstA = smem + mg * 65536 + ng * 1024;
    #pragma unroll
    for (int kk = 0; kk < 8; ++kk) {
        gll16(srcA0 + kk * 64, dstA + kk * 8192);
        gll16(srcA0 + 32 * F_ + kk * 64, dstA + kk * 8192 + 4096);
    }

    // B base for expert 0; advances by H_*F_ per expert
    const unsigned short* bb = w1t + (size_t)(ng * 64 + ln) * F_ + q * 8;
    bf16x8 bc[2][4], bn[2][4];
    #pragma unroll
    for (int ks2 = 0; ks2 < 2; ++ks2)
        #pragma unroll
        for (int nt = 0; nt < 4; ++nt)
            bc[ks2][nt] = *(const bf16x8*)(bb + nt * 16 * F_ + ks2 * 32);

    __syncthreads();   // A-tile staged (drains gll16)

    for (int e = 0; e < E_; ++e) {
        float bias1[4];
        #pragma unroll
        for (int nt = 0; nt < 4; ++nt) bias1[nt] = b1[e * H_ + ng * 64 + nt * 16 + ln];

        f32x4 acc[4][4];
        #pragma unroll
        for (int i = 0; i < 4; ++i)
            #pragma unroll
            for (int j = 0; j < 4; ++j) acc[i][j] = (f32x4){0.f, 0.f, 0.f, 0.f};

        // ---- GEMM1: 8 K-steps, no barriers; B dbuf one K-step ahead ----
        #pragma unroll
        for (int kk = 0; kk < 8; ++kk) {
            const size_t pfo = (kk < 7) ? (size_t)(kk + 1) * 64
                                        : ((e < E_ - 1) ? (size_t)H_ * F_ : 0);
            const unsigned short* pf = bb + pfo;
            #pragma unroll
            for (int ks2 = 0; ks2 < 2; ++ks2)
                #pragma unroll
                for (int nt = 0; nt < 4; ++nt)
                    bn[ks2][nt] = *(const bf16x8*)(pf + nt * 16 * F_ + ks2 * 32);
            #pragma unroll
            for (int ks = 0; ks < 2; ++ks) {
                const int slot = ((ks * 4 + q) ^ (ln & 7)) * 16;
                bf16x8 af[4];
                #pragma unroll
                for (int mt = 0; mt < 4; ++mt)
                    af[mt] = *(const bf16x8*)(smem + mg * 65536 + kk * 8192 + (mt * 16 + ln) * 128 + slot);
                #pragma unroll
                for (int mt = 0; mt < 4; ++mt)
                    #pragma unroll
                    for (int nt = 0; nt < 4; ++nt)
                        acc[mt][nt] = __builtin_amdgcn_mfma_f32_16x16x32_bf16(af[mt], bc[ks][nt], acc[mt][nt], 0, 0, 0);
            }
            #pragma unroll
            for (int ks2 = 0; ks2 < 2; ++ks2)
                #pragma unroll
                for (int nt = 0; nt < 4; ++nt)
                    bc[ks2][nt] = bn[ks2][nt];
        }
        bb += (size_t)H_ * F_;

        // W2 c-slice -> 8 regs, reused across both row-half passes (zero duplication)
        const unsigned short* w2s = w2t + ((size_t)(e * CP2 + w * 16 + ln)) * H_ + q * 8;
        bf16x8 wv[8];
        #pragma unroll
        for (int kc = 0; kc < 8; ++kc)
            wv[kc] = *(const bf16x8*)(w2s + kc * 32);

        // b2 fragment for this wave's c-slice (c = w*16 + q*4 + r2)
        const int c0 = w * 16 + q * 4;
        f32x4 b2f = (f32x4){0.f, 0.f, 0.f, 0.f};
        if (c0 + 3 < C_) b2f = *(const f32x4*)(b2 + e * C_ + c0);

        __syncthreads();   // bar a: previous expert's pass-1 sH reads all done

        // ---- pass 0: rows 0..63 (written by mg==0 waves) ----
        if (mg == 0) {
            #pragma unroll
            for (int mt = 0; mt < 4; ++mt)
                #pragma unroll
                for (int nt = 0; nt < 4; ++nt)
                    #pragma unroll
                    for (int r2 = 0; r2 < 4; ++r2) {
                        int rr = mt * 16 + q * 4 + r2;
                        int hp = ng * 64 + nt * 16 + ln;
                        float v = fmaxf(acc[mt][nt][r2] + bias1[nt], 0.0f);
                        *(unsigned short*)(sH + rr * 512 + ((((hp >> 3) ^ (rr & 31)) << 4)) + ((hp & 7) << 1)) = f2b(v);
                    }
        }
        __syncthreads();   // bar b: pass-0 sH visible

        {
            f32x4 acc2[4];
            #pragma unroll
            for (int nt = 0; nt < 4; ++nt) acc2[nt] = (f32x4){0.f, 0.f, 0.f, 0.f};
            #pragma unroll
            for (int kc = 0; kc < 8; ++kc)
                #pragma unroll
                for (int nt = 0; nt < 4; ++nt) {
                    const int r16 = nt * 16 + ln;
                    bf16x8 hb = *(const bf16x8*)(sH + r16 * 512 + ((((kc * 4 + q) ^ (r16 & 31)) << 4)));
                    acc2[nt] = __builtin_amdgcn_mfma_f32_16x16x32_bf16(wv[kc], hb, acc2[nt], 0, 0, 0);
                }
            if (c0 + 3 < C_) {
                #pragma unroll
                for (int nt = 0; nt < 4; ++nt) {
                    int row = rowBase + nt * 16 + ln;
                    *(f32x4*)(preds + ((size_t)e * B_ + row) * C_ + c0) = acc2[nt] + b2f;
                }
            }
        }
        __syncthreads();   // bar c: pass-0 sH reads done

        // ---- pass 1: rows 64..127 (written by mg==1 waves) ----
        if (mg == 1) {
            #pragma unroll
            for (int mt = 0; mt < 4; ++mt)
                #pragma unroll
                for (int nt = 0; nt < 4; ++nt)
                    #pragma unroll
                    for (int r2 = 0; r2 < 4; ++r2) {
                        int rr = mt * 16 + q * 4 + r2;
                        int hp = ng * 64 + nt * 16 + ln;
                        float v = fmaxf(acc[mt][nt][r2] + bias1[nt], 0.0f);
                        *(unsigned short*)(sH + rr * 512 + ((((hp >> 3) ^ (rr & 31)) << 4)) + ((hp & 7) << 1)) = f2b(v);
                    }
        }
        __syncthreads();   // bar d: pass-1 sH visible

        {
            f32x4 acc2[4];
            #pragma unroll
            for (int nt = 0; nt < 4; ++nt) acc2[nt] = (f32x4){0.f, 0.f, 0.f, 0.f};
            #pragma unroll
            for (int kc = 0; kc < 8; ++kc)
                #pragma unroll
                for (int nt = 0; nt < 4; ++nt) {
                    const int r16 = nt * 16 + ln;
                    bf16x8 hb = *(const bf16x8*)(sH + r16 * 512 + ((((kc * 4 + q) ^ (r16 & 31)) << 4)));
                    acc2[nt] = __builtin_amdgcn_mfma_f32_16x16x32_bf16(wv[kc], hb, acc2[nt], 0, 0, 0);
                }
            if (c0 + 3 < C_) {
                #pragma unroll
                for (int nt = 0; nt < 4; ++nt) {
                    int row = rowBase + 64 + nt * 16 + ln;
                    *(f32x4*)(preds + ((size_t)e * B_ + row) * C_ + c0) = acc2[nt] + b2f;
                }
            }
        }
        // next iteration's bar a protects pass-1 sH reads
    }
}

// ---------------- K3: softmax(preds[e]) for routed experts, combine ----------------
__global__ __launch_bounds__(256) void k3_combine(const float* __restrict__ preds,
                                                  const int* __restrict__ routes,
                                                  float* __restrict__ combined) {
    __shared__ float pbuf[4][104];
    int tid = threadIdx.x, wv = tid >> 6, lane = tid & 63;
    int row = blockIdx.x * 2 + (wv >> 1);
    int rt = routes[row];
    int e = (wv & 1) ? ((rt >> 3) & 7) : (rt & 7);
    const float* pr = preds + ((size_t)e * B_ + row) * C_;
    float a0 = (lane < C_) ? pr[lane] : -1e30f;
    float a1 = (lane + 64 < C_) ? pr[lane + 64] : -1e30f;
    float m = fmaxf(a0, a1);
    #pragma unroll
    for (int off = 32; off; off >>= 1) m = fmaxf(m, __shfl_xor(m, off));
    float s0 = (lane < C_) ? expf(a0 - m) : 0.f;
    float s1 = (lane + 64 < C_) ? expf(a1 - m) : 0.f;
    float s = s0 + s1;
    #pragma unroll
    for (int off = 32; off; off >>= 1) s += __shfl_xor(s, off);
    float inv = 0.5f / s;
    if (lane < C_) pbuf[wv][lane] = s0 * inv;
    if (lane + 64 < C_) pbuf[wv][lane + 64] = s1 * inv;
    __syncthreads();
    if (tid < C_)
        combined[(size_t)(blockIdx.x * 2) * C_ + tid] = pbuf[0][tid] + pbuf[1][tid];
    else if (tid >= 128 && tid < 128 + C_)
        combined[(size_t)(blockIdx.x * 2 + 1) * C_ + (tid - 128)] = pbuf[2][tid - 128] + pbuf[3][tid - 128];
}

extern "C" void kernel_launch(void* const* d_in, const int* in_sizes, int n_in,
                              void* d_out, int out_size, void* d_ws, size_t ws_size,
                              hipStream_t stream) {
    (void)in_sizes; (void)n_in; (void)out_size;
    const float* x  = (const float*)d_in[0];
    const float* W1 = (const float*)d_in[1];
    const float* b1 = (const float*)d_in[2];
    const float* W2 = (const float*)d_in[3];
    const float* b2 = (const float*)d_in[4];
    const float* Wg = (const float*)d_in[5];
    // d_in[6] = k (always 2 per setup)

    float* out = (float*)d_out;
    float* combined = out;                                          // [B][C]
    float* preds = out + (size_t)B_ * C_;                           // [E][B][C]
    float* part  = out + (size_t)B_ * C_ + (size_t)E_ * B_ * C_;    // [E]

    char* ws = (char*)d_ws;
    unsigned short* xbf = (unsigned short*)ws;                      // 33,554,432 B
    unsigned short* w1t = (unsigned short*)(ws + 33554432);         //  2,097,152 B
    unsigned short* w2t = (unsigned short*)(ws + 35651584);         //    524,288 B
    int* routes = (int*)(ws + 36175872);                            //    131,072 B
    if (ws_size < 36306944) return;  // need ~36.3 MB scratch

    hipMemsetAsync(part, 0, E_ * sizeof(float), stream);
    k0_tr_w1<<<dim3(F_ / 32, H_ / 32, E_), dim3(32, 8), 0, stream>>>(W1, w1t);
    k0_cvt_w2<<<(E_ * CP2 * H_ + 255) / 256, 256, 0, stream>>>(W2, w2t);
    k1_gate<<<B_ / 32, 256, 0, stream>>>(x, Wg, xbf, routes, part);
    k2_moe<<<dim3(B_ / 128), 512, 0, stream>>>(xbf, w1t, w2t, b1, b2, preds);
    k3_combine<<<B_ / 2, 256, 0, stream>>>(preds, routes, combined);
}